// Round 3
// baseline (258.313 us; speedup 1.0000x reference)
//
#include <hip/hip_runtime.h>
#include <hip/hip_bf16.h>

// SpectralConv3d: closed-form separable transforms (no FFT needed).
// fwd:  X[bc,k1,k2,k3] = sum_{j1,j2,j3} T[k1,j1]T[k2,j2]T[k3,j3] x[bc,j1,j2,j3]
//       T[k,j] = w_j cos(2*pi*j*k/126), w_0=w_63=1 else 2   (k<16, j<64)
// mix:  low[b,o,m] = sum_i X[b,i,m] W[i,o,m]
// inv:  E (p1, cosA) -> U;  F (p2, cosA) + G (p3, cosB/sinB) -> out
//       cosA[p,j]=cos(2pi j p/64)/64 (p<33), cosB/sinB[p,j]=cos/sin(2pi j p/33)/33 (p<17)

#define PI2 6.283185307179586476925f

// ---------------- init: transform matrices into workspace ----------------
__global__ void k_init(float* __restrict__ Tmat, float* __restrict__ cA,
                       float* __restrict__ cB, float* __restrict__ sB) {
    int t = blockIdx.x * 256 + threadIdx.x;
    if (t < 1024) {
        int k = t >> 6, j = t & 63;
        float w = (j == 0 || j == 63) ? 1.f : 2.f;
        int r = (j * k) % 126;
        Tmat[t] = w * cosf(PI2 * (float)r / 126.f);
    }
    if (t < 528) {
        int p = t >> 4, j = t & 15;
        int r = (j * p) % 64;
        cA[t] = cosf(PI2 * (float)r / 64.f) * (1.f / 64.f);
    }
    if (t < 272) {
        int p = t >> 4, j = t & 15;
        int r = (j * p) % 33;
        float a = PI2 * (float)r / 33.f;
        cB[t] = cosf(a) * (1.f / 33.f);
        sB[t] = sinf(a) * (1.f / 33.f);
    }
}

// ---------------- fused forward: contract j3 then j2 per (bc, j1) ----------------
// A2[bc][j1][k2][k3] = sum_{j2,j3} x[bc,j1,j2,j3] T[k3,j3] T[k2,j2]
// 64 threads = 1 wave; lane = j2. x row lives in registers; phase-1 T reads
// are wave-uniform (scalar-loadable); only tmp (4.3 KB) + Ts (4.3 KB) in LDS.
__global__ __launch_bounds__(64) void k_fwd12(const float* __restrict__ x,
                                              const float* __restrict__ Tmat,
                                              float* __restrict__ A2) {
    __shared__ float tmp[16 * 68];  // tmp[k3][j2], padded
    __shared__ float Ts[16 * 68];   // padded copy of T for phase 2
    const int j1 = blockIdx.x, bc = blockIdx.y;
    const int t = threadIdx.x;

    const float4* Tg4 = (const float4*)Tmat;
    float4* Ts4 = (float4*)Ts;
#pragma unroll
    for (int c = 0; c < 4; c++) {
        int idx = t + 64 * c;  // 256 float4s
        Ts4[(idx >> 4) * 17 + (idx & 15)] = Tg4[idx];
    }

    // x row j2 = t into registers (coalesced 16B/lane)
    const float4* xg = (const float4*)(x + (((size_t)bc * 64 + j1) * 64 + t) * 64);
    float4 xr[16];
#pragma unroll
    for (int q = 0; q < 16; q++) xr[q] = xg[q];

    // phase 1: tmp[k3][t] = sum_j3 x[t][j3] * T[k3][j3]   (T uniform -> s_load)
#pragma unroll 2
    for (int k3 = 0; k3 < 16; k3++) {
        const float4* Trow = Tg4 + k3 * 16;
        float ax = 0.f, ay = 0.f, az = 0.f, aw = 0.f;
#pragma unroll
        for (int q = 0; q < 16; q++) {
            float4 tv = Trow[q];
            ax += xr[q].x * tv.x;
            ay += xr[q].y * tv.y;
            az += xr[q].z * tv.z;
            aw += xr[q].w * tv.w;
        }
        tmp[k3 * 68 + t] = (ax + ay) + (az + aw);
    }
    __syncthreads();

    // phase 2: A2[k2][k3] = sum_j2 tmp[k3][j2] * T[k2][j2]
    // lane: k3 = t&15, k2 = (t>>4) + 4c  -> store addr t + 64c (coalesced)
    const int k3 = t & 15, k2b = t >> 4;
    const float4* tmp4 = (const float4*)tmp;
    float acc2[4] = {0.f, 0.f, 0.f, 0.f};
#pragma unroll
    for (int q = 0; q < 16; q++) {
        float4 tv = tmp4[k3 * 17 + q];
#pragma unroll
        for (int c = 0; c < 4; c++) {
            float4 Tv = Ts4[(k2b + 4 * c) * 17 + q];
            acc2[c] += tv.x * Tv.x + tv.y * Tv.y + tv.z * Tv.z + tv.w * Tv.w;
        }
    }
    float* A2p = A2 + ((size_t)bc * 64 + j1) * 256;
#pragma unroll
    for (int c = 0; c < 4; c++) A2p[t + 64 * c] = acc2[c];
}

// ---------------- forward j1 contraction ----------------
// X[bc][k1][m23] = sum_j1 A2[bc][j1][m23] * T[k1][j1]
__global__ __launch_bounds__(256) void k_fwd3(const float* __restrict__ A2,
                                              const float* __restrict__ Tmat,
                                              float* __restrict__ X) {
    __shared__ float Ts[128];
    const int k1g = blockIdx.x;  // 0..7 -> k1 = 2*k1g, 2*k1g+1
    const int bc = blockIdx.y;
    const int t = threadIdx.x;
    if (t < 128) Ts[t] = Tmat[k1g * 128 + t];
    __syncthreads();
    const float* Ap = A2 + (size_t)bc * 64 * 256 + t;
    float a0 = 0.f, a1 = 0.f;
#pragma unroll 8
    for (int j1 = 0; j1 < 64; j1++) {
        float v = Ap[j1 * 256];
        a0 += v * Ts[j1];
        a1 += v * Ts[64 + j1];
    }
    X[(size_t)bc * 4096 + (size_t)(k1g * 2) * 256 + t] = a0;
    X[(size_t)bc * 4096 + (size_t)(k1g * 2 + 1) * 256 + t] = a1;
}

// ---------------- channel mix ----------------
// low[b,o,m] = sum_i X[b*32+i][m] * W[(i*32+o)][m]; W read exactly once.
__global__ __launch_bounds__(256) void k_mix(const float* __restrict__ X,
                                             const float* __restrict__ W,
                                             float* __restrict__ low) {
    const int mc = blockIdx.x;  // 0..15
    const int o = blockIdx.y;   // 0..31
    const int m = mc * 256 + threadIdx.x;
    const float* Xp = X + m;
    const float* Wp = W + (size_t)o * 4096 + m;
    float acc[4] = {0.f, 0.f, 0.f, 0.f};
#pragma unroll 4
    for (int i = 0; i < 32; i++) {
        float wv = Wp[(size_t)i * 32 * 4096];
#pragma unroll
        for (int b = 0; b < 4; b++)
            acc[b] += Xp[(size_t)(b * 32 + i) * 4096] * wv;
    }
#pragma unroll
    for (int b = 0; b < 4; b++)
        low[((size_t)(b * 32 + o)) * 4096 + m] = acc[b];
}

// ---------------- inverse stage E: p1 contraction ----------------
// U[bo][p1][m23] = sum_k1 low[bo][k1][m23] * cosA[p1][k1]
// block per bo; low slice read once into registers; cA is uniform (s_load).
__global__ __launch_bounds__(256) void k_invE(const float* __restrict__ low,
                                              const float* __restrict__ cA,
                                              float* __restrict__ U) {
    const int bo = blockIdx.x;
    const int t = threadIdx.x;
    const float* lp = low + (size_t)bo * 4096 + t;
    float lr[16];
#pragma unroll
    for (int k1 = 0; k1 < 16; k1++) lr[k1] = lp[k1 << 8];
    float* up = U + (size_t)bo * 33 * 256 + t;
#pragma unroll 1
    for (int p1 = 0; p1 < 33; p1++) {
        const float* ca = cA + p1 * 16;
        float a0 = 0.f, a1 = 0.f, a2 = 0.f, a3 = 0.f;
#pragma unroll
        for (int k1 = 0; k1 < 16; k1 += 4) {
            a0 += lr[k1] * ca[k1];
            a1 += lr[k1 + 1] * ca[k1 + 1];
            a2 += lr[k1 + 2] * ca[k1 + 2];
            a3 += lr[k1 + 3] * ca[k1 + 3];
        }
        up[p1 * 256] = (a0 + a1) + (a2 + a3);
    }
}

// ---------------- inverse stages F+G per (bo, p1) ----------------
__global__ __launch_bounds__(256) void k_invFG(const float* __restrict__ U,
                                               const float* __restrict__ cA,
                                               const float* __restrict__ cB,
                                               const float* __restrict__ sB,
                                               float* __restrict__ out) {
    __shared__ float c1[256];
    __shared__ float c2[528];
    __shared__ float cAs[528], cBs[272], sBs[272];
    const int p1 = blockIdx.x, bo = blockIdx.y;
    const int t = threadIdx.x;

    c1[t] = U[((size_t)bo * 33 + p1) * 256 + t];
    for (int c = t; c < 528; c += 256) cAs[c] = cA[c];
    for (int c = t; c < 272; c += 256) { cBs[c] = cB[c]; sBs[c] = sB[c]; }
    __syncthreads();

    // F: c2[p2*16+k3] = sum_k2 c1[k2*16+k3] * cosA[p2][k2]
    for (int idx = t; idx < 528; idx += 256) {
        int p2 = idx >> 4, k3 = idx & 15;
        float acc = 0.f;
#pragma unroll
        for (int k2 = 0; k2 < 16; k2++) acc += c1[(k2 << 4) + k3] * cAs[p2 * 16 + k2];
        c2[idx] = acc;
    }
    __syncthreads();

    // G: out[p2][p3][{re,im}] = sum_k3 c2[p2][k3] * cosB/sinB[p3][k3]
    float* op = out + ((size_t)bo * 33 + p1) * 33 * 17 * 2;
    for (int idx = t; idx < 1122; idx += 256) {
        int p2 = idx / 34, rem = idx % 34;
        int p3 = rem >> 1, cc = rem & 1;
        const float* M = cc ? sBs : cBs;
        float acc = 0.f;
#pragma unroll
        for (int k3 = 0; k3 < 16; k3++) acc += c2[(p2 << 4) + k3] * M[p3 * 16 + k3];
        op[idx] = acc;
    }
}

extern "C" void kernel_launch(void* const* d_in, const int* in_sizes, int n_in,
                              void* d_out, int out_size, void* d_ws, size_t ws_size,
                              hipStream_t stream) {
    const float* x = (const float*)d_in[0];   // (4,32,64,64,64)
    const float* W = (const float*)d_in[1];   // (32,32,16,16,16)
    float* out = (float*)d_out;               // (4,32,33,33,17,2)

    float* ws = (float*)d_ws;
    float* Tmat = ws;                 // 1024
    float* cA   = ws + 1024;          // 528
    float* cB   = ws + 1552;          // 272
    float* sB   = ws + 1824;          // 272
    float* A2   = ws + 4096;          // 128*64*256 = 2097152
    float* X    = A2 + 2097152;       // 128*4096   = 524288
    float* low  = X + 524288;         // 128*4096   = 524288
    float* U    = low + 524288;       // 128*33*256 = 1081344

    k_init<<<dim3(4), dim3(256), 0, stream>>>(Tmat, cA, cB, sB);
    k_fwd12<<<dim3(64, 128), dim3(64), 0, stream>>>(x, Tmat, A2);
    k_fwd3<<<dim3(8, 128), dim3(256), 0, stream>>>(A2, Tmat, X);
    k_mix<<<dim3(16, 32), dim3(256), 0, stream>>>(X, W, low);
    k_invE<<<dim3(128), dim3(256), 0, stream>>>(low, cA, U);
    k_invFG<<<dim3(33, 128), dim3(256), 0, stream>>>(U, cA, cB, sB, out);
}